// Round 14
// baseline (598.372 us; speedup 1.0000x reference)
//
#include <hip/hip_runtime.h>
#include <hip/hip_bf16.h>

#define M_BATCH 65536
#define K_IN    1024
#define N_OUT   256
#define TAU     0.0625f

// d_ws layout (shorts): xhi [65536][1024], xlo [65536][1024], wt [256][1024]
#define XLO_SOFF 67108864ULL
#define WT_SOFF  134217728ULL
#define WS_NEED  268959744ULL   // bytes

typedef __attribute__((ext_vector_type(8))) short short8;
typedef __attribute__((ext_vector_type(4))) short short4v;
typedef __attribute__((ext_vector_type(4))) float f32x4;

__device__ inline short f2bf(float f) {
    __hip_bfloat16 h = __float2bfloat16(f);
    return __builtin_bit_cast(short, h);
}
__device__ inline float bf2f(short s) {
    unsigned u = ((unsigned)(unsigned short)s) << 16;
    return __builtin_bit_cast(float, u);
}
__device__ inline void gload16(const void* g, void* lds) {
    __builtin_amdgcn_global_load_lds(
        (const __attribute__((address_space(1))) unsigned int*)g,
        (__attribute__((address_space(3))) unsigned int*)lds, 16, 0, 0);
}

// x -> swizzled bf16 hi/lo. Quarter q of each 32-k block stored at
// q ^ ((row>>1)&3): conflict-free ds_read with LINEAR LDS (rule #21).
__global__ __launch_bounds__(512) void presplit_sw(const float* __restrict__ x,
                                                   short* __restrict__ xhi,
                                                   short* __restrict__ xlo) {
    const int stride = gridDim.x * 512;
    for (int idx = blockIdx.x * 512 + threadIdx.x; idx < M_BATCH * (K_IN / 4); idx += stride) {
        const int row  = idx >> 8;
        const int col4 = idx & 255;
        const float4 v = ((const float4*)x)[idx];
        short4v h, l;
        h.x = f2bf(v.x); l.x = f2bf(v.x - bf2f(h.x));
        h.y = f2bf(v.y); l.y = f2bf(v.y - bf2f(h.y));
        h.z = f2bf(v.z); l.z = f2bf(v.z - bf2f(h.z));
        h.w = f2bf(v.w); l.w = f2bf(v.w - bf2f(h.w));
        const int kt = col4 >> 3;
        const int q  = (col4 >> 1) & 3;
        const int qp = q ^ ((row >> 1) & 3);
        const size_t dst = (size_t)row * K_IN + kt * 32 + qp * 8 + (col4 & 1) * 4;
        *(short4v*)(xhi + dst) = h;
        *(short4v*)(xlo + dst) = l;
    }
}

__global__ __launch_bounds__(512) void wconv_sw(const float* __restrict__ w,
                                                short* __restrict__ wt) {
    const int idx  = blockIdx.x * 512 + threadIdx.x;   // 65536 float4 total
    const int row  = idx >> 8;
    const int col4 = idx & 255;
    const float4 v = ((const float4*)w)[idx];
    short4v h;
    h.x = f2bf(v.x); h.y = f2bf(v.y); h.z = f2bf(v.z); h.w = f2bf(v.w);
    const int kt = col4 >> 3;
    const int q  = (col4 >> 1) & 3;
    const int qp = q ^ ((row >> 1) & 3);
    *(short4v*)(wt + (size_t)row * K_IN + kt * 32 + qp * 8 + (col4 & 1) * 4) = h;
}

// main: pure-bf16 MFMA GEMM staged via global_load_lds. BM=128, BN=256,
// BK=32, double-buffered (LDS 64KB), one barrier per K-step.
// Band cells |t+0.5| < TAU -> C3-exact recompute (r8..r13-verified ordering).
__global__ __launch_bounds__(512) void binlin_gl(const float* __restrict__ x,
                                                 const float* __restrict__ wf,
                                                 const short* __restrict__ xhi,
                                                 const short* __restrict__ xlo,
                                                 const short* __restrict__ wt,
                                                 const float* __restrict__ bias,
                                                 const float* __restrict__ sign,
                                                 float* __restrict__ out) {
    __shared__ __align__(16) unsigned char smem[65536];

    const int tid  = threadIdx.x;
    const int lane = tid & 63;
    const int wid  = tid >> 6;
    const int wm   = wid >> 2;
    const int wn   = wid & 3;
    const int l15  = lane & 15;
    const int l4   = lane >> 4;
    const int m0   = blockIdx.x * 128;

    const int arow = wid * 16 + (lane >> 2);
    const int aq   = lane & 3;
    const size_t asrc  = (size_t)(m0 + arow) * K_IN + aq * 8;
    const int wrow = wid * 32 + (lane >> 2);
    const size_t wsrc0 = (size_t)wrow * K_IN + aq * 8;
    const size_t wsrc1 = (size_t)(wrow + 16) * K_IN + aq * 8;
    const int aldsoff = wid * 1024;
    const int wldsoff = wid * 2048;

    int aoff[4], boff[4];
#pragma unroll
    for (int mi = 0; mi < 4; ++mi) {
        const int R = wm * 64 + mi * 16 + l15;
        aoff[mi] = R * 64 + ((l4 ^ ((R >> 1) & 3)) << 4);
    }
#pragma unroll
    for (int ni = 0; ni < 4; ++ni) {
        const int N = wn * 64 + ni * 16 + l15;
        boff[ni] = N * 64 + ((l4 ^ ((N >> 1) & 3)) << 4);
    }

    f32x4 acc[4][4];
#pragma unroll
    for (int i = 0; i < 4; ++i)
#pragma unroll
        for (int j = 0; j < 4; ++j) acc[i][j] = (f32x4){0.f, 0.f, 0.f, 0.f};

#define STAGE(BASE, KT) {                                                   \
        gload16(xhi + asrc + (KT) * 32, smem + (BASE) + aldsoff);           \
        gload16(xlo + asrc + (KT) * 32, smem + (BASE) + 8192 + aldsoff);    \
        gload16(wt + wsrc0 + (KT) * 32, smem + (BASE) + 16384 + wldsoff);   \
        gload16(wt + wsrc1 + (KT) * 32, smem + (BASE) + 16384 + wldsoff + 1024); }

#define MSTEP(BASE) {                                                       \
        short8 bfr[4];                                                      \
        _Pragma("unroll")                                                   \
        for (int ni = 0; ni < 4; ++ni)                                      \
            bfr[ni] = *(const short8*)(smem + (BASE) + 16384 + boff[ni]);   \
        _Pragma("unroll")                                                   \
        for (int mi = 0; mi < 4; ++mi) {                                    \
            const short8 ahi = *(const short8*)(smem + (BASE) + aoff[mi]);  \
            const short8 alo = *(const short8*)(smem + (BASE) + 8192 + aoff[mi]); \
            _Pragma("unroll")                                               \
            for (int ni = 0; ni < 4; ++ni) {                                \
                acc[mi][ni] = __builtin_amdgcn_mfma_f32_16x16x32_bf16(      \
                    ahi, bfr[ni], acc[mi][ni], 0, 0, 0);                    \
                acc[mi][ni] = __builtin_amdgcn_mfma_f32_16x16x32_bf16(      \
                    alo, bfr[ni], acc[mi][ni], 0, 0, 0);                    \
            }                                                               \
        }                                                                   }

    STAGE(0, 0)
    __syncthreads();

    for (int it = 0; it < 16; ++it) {
        const int kt = it * 2;
        if (kt + 1 < 32) STAGE(32768, kt + 1)
        MSTEP(0)
        __syncthreads();
        if (kt + 2 < 32) STAGE(0, kt + 2)
        MSTEP(32768)
        __syncthreads();
    }

    unsigned char* dec = (unsigned char*)smem;
#pragma unroll
    for (int ni = 0; ni < 4; ++ni) {
        const int n = wn * 64 + ni * 16 + l15;
        const float b = bias[n];
        const float s = sign[n];
#pragma unroll
        for (int mi = 0; mi < 4; ++mi) {
            const int ml = wm * 64 + mi * 16 + l4 * 4;
#pragma unroll
            for (int j = 0; j < 4; ++j) {
                const float t = (acc[mi][ni][j] + b) * s;
                unsigned char d;
                if (fabsf(t + 0.5f) < TAU) {
                    const float* xr_ = x + (size_t)(m0 + ml + j) * K_IN;
                    const float* wr_ = wf + (size_t)n * K_IN;
                    float a0 = 0.f, a1 = 0.f;
                    for (int k4 = 0; k4 < 128; ++k4) {
                        const float4 xv0 = *(const float4*)(xr_ + k4 * 4);
                        const float4 wv0 = *(const float4*)(wr_ + k4 * 4);
                        const float4 xv1 = *(const float4*)(xr_ + 512 + k4 * 4);
                        const float4 wv1 = *(const float4*)(wr_ + 512 + k4 * 4);
                        a0 = fmaf(xv0.x, wv0.x, a0); a1 = fmaf(xv1.x, wv1.x, a1);
                        a0 = fmaf(xv0.y, wv0.y, a0); a1 = fmaf(xv1.y, wv1.y, a1);
                        a0 = fmaf(xv0.z, wv0.z, a0); a1 = fmaf(xv1.z, wv1.z, a1);
                        a0 = fmaf(xv0.w, wv0.w, a0); a1 = fmaf(xv1.w, wv1.w, a1);
                    }
                    const float tt = ((a0 + a1) + b) * s;
                    d = (tt >= -0.5f) ? 1 : 0;
                } else {
                    d = (t >= -0.5f) ? 1 : 0;
                }
                dec[(ml + j) * N_OUT + n] = d;
            }
        }
    }
    __syncthreads();

#pragma unroll
    for (int it = 0; it < 16; ++it) {
        const int f   = it * 512 + tid;
        const int row = f >> 6;
        const int c4  = f & 63;
        const uchar4 dv = *(const uchar4*)&dec[row * N_OUT + c4 * 4];
        *(float4*)(out + (size_t)(m0 + row) * N_OUT + c4 * 4) =
            make_float4((float)dv.x, (float)dv.y, (float)dv.z, (float)dv.w);
    }
}

// ---- fallback (r9-proven, 636us): fp32 tiled GEMM + C3 band fixup ----
__global__ __launch_bounds__(256) void binlin_fast(const float* __restrict__ x,
                                                   const float* __restrict__ w,
                                                   const float* __restrict__ bias,
                                                   const float* __restrict__ sign,
                                                   float* __restrict__ out) {
    __shared__ float As[32][132];
    __shared__ float Bs[32][132];
    const int tid = threadIdx.x;
    const int tx  = tid & 15;
    const int ty  = tid >> 4;
    const int n0  = blockIdx.x * 128;
    const int m0  = blockIdx.y * 128;
    const int sr  = tid >> 3;
    const int sc  = (tid & 7) * 4;
    float acc[8][8];
#pragma unroll
    for (int i = 0; i < 8; ++i)
#pragma unroll
        for (int j = 0; j < 8; ++j) acc[i][j] = 0.f;
    for (int kt = 0; kt < K_IN; kt += 32) {
        __syncthreads();
#pragma unroll
        for (int q = 0; q < 4; ++q) {
            const int row = sr + q * 32;
            const float4 va = *(const float4*)(x + (size_t)(m0 + row) * K_IN + kt + sc);
            As[sc + 0][row] = va.x; As[sc + 1][row] = va.y;
            As[sc + 2][row] = va.z; As[sc + 3][row] = va.w;
            const float4 vb = *(const float4*)(w + (size_t)(n0 + row) * K_IN + kt + sc);
            Bs[sc + 0][row] = vb.x; Bs[sc + 1][row] = vb.y;
            Bs[sc + 2][row] = vb.z; Bs[sc + 3][row] = vb.w;
        }
        __syncthreads();
#pragma unroll
        for (int kk = 0; kk < 32; ++kk) {
            const float4 a0 = *(const float4*)&As[kk][ty * 8];
            const float4 a1 = *(const float4*)&As[kk][ty * 8 + 4];
            const float4 b0 = *(const float4*)&Bs[kk][tx * 8];
            const float4 b1 = *(const float4*)&Bs[kk][tx * 8 + 4];
            const float a[8] = {a0.x, a0.y, a0.z, a0.w, a1.x, a1.y, a1.z, a1.w};
            const float b[8] = {b0.x, b0.y, b0.z, b0.w, b1.x, b1.y, b1.z, b1.w};
#pragma unroll
            for (int i = 0; i < 8; ++i)
#pragma unroll
                for (int j = 0; j < 8; ++j)
                    acc[i][j] = fmaf(a[i], b[j], acc[i][j]);
        }
    }
    const int nb = n0 + tx * 8;
    float bv[8], sv[8];
#pragma unroll
    for (int j = 0; j < 8; ++j) { bv[j] = bias[nb + j]; sv[j] = sign[nb + j]; }
#pragma unroll
    for (int i = 0; i < 8; ++i) {
        const int m = m0 + ty * 8 + i;
        float o[8];
#pragma unroll
        for (int j = 0; j < 8; ++j) {
            const float t = (acc[i][j] + bv[j]) * sv[j];
            if (fabsf(t + 0.5f) < TAU) {
                const float* xr = x + (size_t)m * K_IN;
                const float* wr = w + (size_t)(nb + j) * K_IN;
                float cs = 0.f;
                for (int p = 0; p < 2; ++p) {
                    float a = 0.f;
                    const int kb = p * 512;
                    for (int k4 = 0; k4 < 128; ++k4) {
                        const float4 xv = *(const float4*)(xr + kb + k4 * 4);
                        const float4 wv = *(const float4*)(wr + kb + k4 * 4);
                        a = fmaf(xv.x, wv.x, a); a = fmaf(xv.y, wv.y, a);
                        a = fmaf(xv.z, wv.z, a); a = fmaf(xv.w, wv.w, a);
                    }
                    cs += a;
                }
                o[j] = (((cs + bv[j]) * sv[j]) >= -0.5f) ? 1.0f : 0.0f;
            } else {
                o[j] = (t >= -0.5f) ? 1.0f : 0.0f;
            }
        }
        float4* op = (float4*)(out + (size_t)m * N_OUT + nb);
        op[0] = make_float4(o[0], o[1], o[2], o[3]);
        op[1] = make_float4(o[4], o[5], o[6], o[7]);
    }
}

extern "C" void kernel_launch(void* const* d_in, const int* in_sizes, int n_in,
                              void* d_out, int out_size, void* d_ws, size_t ws_size,
                              hipStream_t stream) {
    const float* x    = (const float*)d_in[0];
    const float* w    = (const float*)d_in[1];
    const float* bias = (const float*)d_in[2];
    const float* sign = (const float*)d_in[3];

    if (n_in >= 4 && in_sizes[0] != M_BATCH * K_IN) {   // defensive no-op
        const float* small[2] = {nullptr, nullptr};
        int nsmall = 0;
        for (int i = 0; i < 4; ++i) {
            if (in_sizes[i] == M_BATCH * K_IN)      x = (const float*)d_in[i];
            else if (in_sizes[i] == N_OUT * K_IN)   w = (const float*)d_in[i];
            else if (nsmall < 2) small[nsmall++] = (const float*)d_in[i];
        }
        if (nsmall == 2) { bias = small[0]; sign = small[1]; }
    }

    float* out = (float*)d_out;

    if (ws_size >= WS_NEED) {
        short* xhi = (short*)d_ws;
        short* xlo = xhi + XLO_SOFF;
        short* wtp = xhi + WT_SOFF;
        presplit_sw<<<2048, 512, 0, stream>>>(x, xhi, xlo);
        wconv_sw<<<128, 512, 0, stream>>>(w, wtp);
        binlin_gl<<<M_BATCH / 128, 512, 0, stream>>>(x, w, xhi, xlo, wtp, bias, sign, out);
    } else {
        dim3 grid(N_OUT / 128, M_BATCH / 128);
        binlin_fast<<<grid, 256, 0, stream>>>(x, w, bias, sign, out);
    }
}